// Round 6
// baseline (433.992 us; speedup 1.0000x reference)
//
#include <hip/hip_runtime.h>
#include <hip/hip_bf16.h>
#include <math.h>

// Problem constants (B=32, H=W=56, C=256, heads=8, hd=32, ws=7)
#define NTOK 3136            // 56*56
#define C_ 256
#define HEADS_ 8
#define HD 32
#define WS_ 7
#define L_ 49
#define NWIN 2048            // 32 * 8 * 8
#define NWH 16384            // NWIN * HEADS_
#define M_ 100352            // NWIN * 49  == BATCH*NTOK
#define MLPH 512
#define WHSZ 2048            // 64 (padded L) * 32 (hd) elems per (win,head) plane

typedef __bf16 bf16x8 __attribute__((ext_vector_type(8)));
typedef float f32x4 __attribute__((ext_vector_type(4)));

__device__ __forceinline__ unsigned short f2bf(float f) {
    union { float f; unsigned u; } v; v.f = f;
    unsigned r = v.u + 0x7fffu + ((v.u >> 16) & 1u);   // RNE
    return (unsigned short)(r >> 16);
}
__device__ __forceinline__ float bf2f(unsigned short s) {
    union { unsigned u; float f; } v; v.u = ((unsigned)s) << 16;
    return v.f;
}

// windowed token index -> natural row index
__device__ __forceinline__ int t2rr(int t) {
    int win = t / L_;
    int l   = t - win * L_;
    int b_  = win >> 6, wh = (win >> 3) & 7, ww = win & 7;
    int ld7 = l / WS_;
    int y   = wh * WS_ + ld7;
    int xc  = ww * WS_ + (l - ld7 * WS_);
    return b_ * NTOK + y * 56 + xc;
}

// XCD-chunked bm-major remap: all bn-tiles of a bm-chunk stay on one XCD so
// the A stripe is fetched from HBM once (L2-resident for the chunk).
template <int NBN>
__device__ __forceinline__ void xcd_decode(int nb, int& bm, int& bn) {
    int h = blockIdx.x;
    int fid = (h & 7) * (nb >> 3) + (h >> 3);
    int bmi = fid / NBN;
    bm = bmi * 128;
    bn = (fid - bmi * NBN) * 128;
}

// ---------------------------------------------------------------------------
__global__ __launch_bounds__(256) void cvt_kernel(
    const float* __restrict__ in, unsigned short* __restrict__ out, int n)
{
    int i = blockIdx.x * 256 + threadIdx.x;
    if (i < n) out[i] = f2bf(in[i]);
}

// ---------------------------------------------------------------------------
// LN1: one wave per token, 4 floats/lane; bf16 output in windowed row order.
// ---------------------------------------------------------------------------
__global__ __launch_bounds__(256) void ln_kernel(
    const float* __restrict__ x, const float* __restrict__ gamma,
    const float* __restrict__ beta, unsigned short* __restrict__ out)
{
    int wave = threadIdx.x >> 6;
    int lane = threadIdx.x & 63;
    int p = blockIdx.x * 4 + wave;
    const float* row = x + (size_t)p * C_;
    float4 v = *(const float4*)(row + lane * 4);
    float s  = v.x + v.y + v.z + v.w;
    float ss = v.x * v.x + v.y * v.y + v.z * v.z + v.w * v.w;
    #pragma unroll
    for (int m = 1; m < 64; m <<= 1) {
        s  += __shfl_xor(s, m, 64);
        ss += __shfl_xor(ss, m, 64);
    }
    float mean = s * (1.0f / C_);
    float var  = ss * (1.0f / C_) - mean * mean;
    float inv  = rsqrtf(var + 1e-5f);
    float4 gv = *(const float4*)(gamma + lane * 4);
    float4 bv = *(const float4*)(beta + lane * 4);
    int b_ = p / NTOK, n = p - b_ * NTOK;
    int y = n / 56, xc = n - y * 56;
    int win = (b_ * 8 + y / WS_) * 8 + xc / WS_;
    int l   = (y % WS_) * WS_ + (xc % WS_);
    size_t orow = (size_t)(win * L_ + l) * C_;
    unsigned short o[4];
    o[0] = f2bf((v.x - mean) * inv * gv.x + bv.x);
    o[1] = f2bf((v.y - mean) * inv * gv.y + bv.y);
    o[2] = f2bf((v.z - mean) * inv * gv.z + bv.z);
    o[3] = f2bf((v.w - mean) * inv * gv.w + bv.w);
    *(uint2*)(out + orow + lane * 4) = *(const uint2*)o;
}

// ---------------------------------------------------------------------------
#define GBM 128
#define GBN 128
#define GBK 32

__device__ __forceinline__ void gload_lds16(const void* g, void* l) {
    __builtin_amdgcn_global_load_lds(
        (const __attribute__((address_space(1))) unsigned*)g,
        (__attribute__((address_space(3))) unsigned*)l, 16, 0, 0);
}

// ---------------------------------------------------------------------------
// mgemm: 128x128 tile, 256 threads, double-buffered 1-barrier K-loop with
// T2 LDS swizzle. EPI 0: QKV scatter. EPI 2: GELU (fc1).
// ---------------------------------------------------------------------------
template <int EPI, int NBN>
__global__ __launch_bounds__(256) void mgemm(
    const unsigned short* __restrict__ A, const unsigned short* __restrict__ W,
    const float* __restrict__ bias, void* __restrict__ outv,
    int M, int N, int K)
{
    __shared__ __align__(16) unsigned short As0[GBM * GBK], As1[GBM * GBK];
    __shared__ __align__(16) unsigned short Bs0[GBN * GBK], Bs1[GBN * GBK];

    int tid  = threadIdx.x;
    int w    = tid >> 6;
    int lane = tid & 63;
    int wr = w >> 1, wc = w & 1;
    int bm, bn;
    xcd_decode<NBN>(gridDim.x, bm, bn);
    int srow = lane >> 2;
    int scol = ((lane & 3) ^ ((lane >> 3) & 3)) * 8;  // T2 inverse-swizzled src
    int c = lane & 15, hi = lane >> 4;
    int hs = (hi ^ ((c >> 1) & 3)) * 8;               // T2 swizzled read chunk

    f32x4 acc[4][4] = {};

    auto stage = [&](unsigned short* asd, unsigned short* bsd, int k0) {
        #pragma unroll
        for (int i = 0; i < 2; ++i) {
            int ra = w * 32 + i * 16;
            gload_lds16(A + (size_t)(bm + ra + srow) * K + k0 + scol, asd + ra * GBK);
            gload_lds16(W + (size_t)(bn + ra + srow) * K + k0 + scol, bsd + ra * GBK);
        }
    };
    auto frags = [&](const unsigned short* asd, const unsigned short* bsd,
                     bf16x8* af, bf16x8* bf) {
        #pragma unroll
        for (int mi = 0; mi < 4; ++mi)
            af[mi] = *(const bf16x8*)&asd[(wr * 64 + mi * 16 + c) * GBK + hs];
        #pragma unroll
        for (int ni = 0; ni < 4; ++ni)
            bf[ni] = *(const bf16x8*)&bsd[(wc * 64 + ni * 16 + c) * GBK + hs];
    };
    auto domfma = [&](bf16x8* af, bf16x8* bf) {
        #pragma unroll
        for (int mi = 0; mi < 4; ++mi)
            #pragma unroll
            for (int ni = 0; ni < 4; ++ni)
                acc[mi][ni] = __builtin_amdgcn_mfma_f32_16x16x32_bf16(
                    af[mi], bf[ni], acc[mi][ni], 0, 0, 0);
    };

    int NT = K / GBK;
    stage(As0, Bs0, 0);
    __syncthreads();
    for (int t = 0; t < NT; t += 2) {
        {
            bf16x8 af[4], bf[4];
            frags(As0, Bs0, af, bf);
            if (t + 1 < NT) stage(As1, Bs1, (t + 1) * GBK);
            domfma(af, bf);
            __syncthreads();
        }
        if (t + 1 < NT) {
            bf16x8 af[4], bf[4];
            frags(As1, Bs1, af, bf);
            if (t + 2 < NT) stage(As0, Bs0, (t + 2) * GBK);
            domfma(af, bf);
            __syncthreads();
        }
    }

    // epilogue: C/D layout col=lane&15, row=(lane>>4)*4+reg  [m89-verified]
    #pragma unroll
    for (int mi = 0; mi < 4; ++mi) {
        #pragma unroll
        for (int r = 0; r < 4; ++r) {
            int row = bm + wr * 64 + mi * 16 + hi * 4 + r;
            int win, l;
            if (EPI == 0) { win = row / L_; l = row - win * L_; }
            #pragma unroll
            for (int ni = 0; ni < 4; ++ni) {
                int col = bn + wc * 64 + ni * 16 + c;
                float val = acc[mi][ni][r] + bias[col];
                if (EPI == 0) {
                    int which = col >> 8;
                    int head  = (col >> 5) & 7;
                    int d     = col & 31;
                    int wh = win * HEADS_ + head;
                    size_t base = (size_t)which * ((size_t)NWH * WHSZ) + (size_t)wh * WHSZ;
                    size_t off;
                    if (which == 2)
                        off = base + (size_t)(((l >> 3) * HD + d) << 3) + (l & 7);
                    else
                        off = base + (size_t)l * HD + d;
                    ((unsigned short*)outv)[off] = f2bf(val);
                } else {
                    float g = 0.5f * val * (1.0f + erff(val * 0.70710678118654752f));
                    ((unsigned short*)outv)[(size_t)row * N + col] = f2bf(g);
                }
            }
        }
    }
}

// ---------------------------------------------------------------------------
// mgemm_ln: out-proj (M x 256 = o_win @ wout^T + bout) fused with residual
// (x gathered windowed) and LN2. 512 threads, block = 128 rows x 256 cols.
// Double-buffered K-loop + T2 swizzle; staging LDS aliased with X1 stage.
// Outputs (both bf16, windowed-sequential): x1 and ln2(x1).
// ---------------------------------------------------------------------------
#define XS 260     // padded X1 stage row stride (shorts)

__global__ __launch_bounds__(512) void mgemm_ln(
    const unsigned short* __restrict__ A, const unsigned short* __restrict__ W,
    const float* __restrict__ bias, const float* __restrict__ x,
    const float* __restrict__ g2, const float* __restrict__ b2,
    unsigned short* __restrict__ x1_out, unsigned short* __restrict__ ln_out)
{
    __shared__ __align__(16) unsigned short pool[128 * XS];   // 65 KB
    unsigned short* As0 = pool;             // 4096
    unsigned short* As1 = pool + 4096;
    unsigned short* Bs0 = pool + 8192;      // 8192
    unsigned short* Bs1 = pool + 16384;     // ends at 24576

    int tid  = threadIdx.x;
    int w    = tid >> 6;          // 0..7
    int lane = tid & 63;
    int wr = w >> 2, wc = w & 3;  // 2 x 4 wave tiles of 64x64
    int bm = blockIdx.x * 128;
    int srow = lane >> 2;
    int scol = ((lane & 3) ^ ((lane >> 3) & 3)) * 8;
    int c = lane & 15, hi = lane >> 4;
    int hs = (hi ^ ((c >> 1) & 3)) * 8;

    f32x4 acc[4][4] = {};

    auto stage = [&](unsigned short* asd, unsigned short* bsd, int k0) {
        gload_lds16(A + (size_t)(bm + w * 16 + srow) * 256 + k0 + scol,
                    asd + (w * 16) * 32);
        #pragma unroll
        for (int i = 0; i < 2; ++i) {
            int ra = w * 32 + i * 16;
            gload_lds16(W + (size_t)(ra + srow) * 256 + k0 + scol, bsd + ra * 32);
        }
    };
    auto frags = [&](const unsigned short* asd, const unsigned short* bsd,
                     bf16x8* af, bf16x8* bf) {
        #pragma unroll
        for (int mi = 0; mi < 4; ++mi)
            af[mi] = *(const bf16x8*)&asd[(wr * 64 + mi * 16 + c) * 32 + hs];
        #pragma unroll
        for (int ni = 0; ni < 4; ++ni)
            bf[ni] = *(const bf16x8*)&bsd[(wc * 64 + ni * 16 + c) * 32 + hs];
    };
    auto domfma = [&](bf16x8* af, bf16x8* bf) {
        #pragma unroll
        for (int mi = 0; mi < 4; ++mi)
            #pragma unroll
            for (int ni = 0; ni < 4; ++ni)
                acc[mi][ni] = __builtin_amdgcn_mfma_f32_16x16x32_bf16(
                    af[mi], bf[ni], acc[mi][ni], 0, 0, 0);
    };

    stage(As0, Bs0, 0);
    __syncthreads();
    for (int t = 0; t < 8; t += 2) {
        {
            bf16x8 af[4], bf[4];
            frags(As0, Bs0, af, bf);
            stage(As1, Bs1, (t + 1) * 32);
            domfma(af, bf);
            __syncthreads();
        }
        {
            bf16x8 af[4], bf[4];
            frags(As1, Bs1, af, bf);
            if (t + 2 < 8) stage(As0, Bs0, (t + 2) * 32);
            domfma(af, bf);
            __syncthreads();
        }
    }

    // stage o (+bias) to LDS as bf16 (aliases staging buffers; barrier above)
    #pragma unroll
    for (int mi = 0; mi < 4; ++mi) {
        #pragma unroll
        for (int ni = 0; ni < 4; ++ni) {
            int colb = wc * 64 + ni * 16 + c;
            float bv = bias[colb];
            #pragma unroll
            for (int r = 0; r < 4; ++r)
                pool[(wr * 64 + mi * 16 + hi * 4 + r) * XS + colb] =
                    f2bf(acc[mi][ni][r] + bv);
        }
    }
    __syncthreads();

    // row phase: wave w handles rows [w*16, w*16+16); lane owns 4 cols
    float4 gv = *(const float4*)(g2 + lane * 4);
    float4 bv2 = *(const float4*)(b2 + lane * 4);
    #pragma unroll 2
    for (int i = 0; i < 16; ++i) {
        int tl = w * 16 + i;
        int t = bm + tl;
        int rr = t2rr(t);
        float4 xv = *(const float4*)(x + (size_t)rr * C_ + lane * 4);
        uint2 ov = *(const uint2*)&pool[tl * XS + lane * 4];
        float x0 = xv.x + bf2f(ov.x & 0xffff);
        float x1 = xv.y + bf2f(ov.x >> 16);
        float x2 = xv.z + bf2f(ov.y & 0xffff);
        float x3 = xv.w + bf2f(ov.y >> 16);
        float s  = x0 + x1 + x2 + x3;
        float ss = x0 * x0 + x1 * x1 + x2 * x2 + x3 * x3;
        #pragma unroll
        for (int m = 1; m < 64; m <<= 1) {
            s  += __shfl_xor(s, m, 64);
            ss += __shfl_xor(ss, m, 64);
        }
        float mean = s * (1.0f / C_);
        float var  = ss * (1.0f / C_) - mean * mean;
        float inv  = rsqrtf(var + 1e-5f);
        uint2 xw, lw;
        xw.x = (unsigned)f2bf(x0) | ((unsigned)f2bf(x1) << 16);
        xw.y = (unsigned)f2bf(x2) | ((unsigned)f2bf(x3) << 16);
        float l0 = (x0 - mean) * inv * gv.x + bv2.x;
        float l1 = (x1 - mean) * inv * gv.y + bv2.y;
        float l2 = (x2 - mean) * inv * gv.z + bv2.z;
        float l3 = (x3 - mean) * inv * gv.w + bv2.w;
        lw.x = (unsigned)f2bf(l0) | ((unsigned)f2bf(l1) << 16);
        lw.y = (unsigned)f2bf(l2) | ((unsigned)f2bf(l3) << 16);
        *(uint2*)(x1_out + (size_t)t * C_ + lane * 4) = xw;
        *(uint2*)(ln_out + (size_t)t * C_ + lane * 4) = lw;
    }
}

// ---------------------------------------------------------------------------
// mgemm_out: fc2 (M x 256 = gelu @ w2^T + b2) + residual (x1 bf16, windowed)
// Double-buffered K-loop (K=512) + T2 swizzle; LDS-transposed epilogue ->
// fully coalesced natural-order f32 writes. XCD-chunked remap (NBN=2).
// ---------------------------------------------------------------------------
__global__ __launch_bounds__(256) void mgemm_out(
    const unsigned short* __restrict__ A, const unsigned short* __restrict__ W,
    const float* __restrict__ bias, const unsigned short* __restrict__ x1,
    float* __restrict__ dout)
{
    __shared__ __align__(16) unsigned short pool[16384];     // 32 KB
    unsigned short* As0 = pool;
    unsigned short* As1 = pool + 4096;
    unsigned short* Bs0 = pool + 8192;
    unsigned short* Bs1 = pool + 12288;
    float* stg = (float*)pool;                               // 32 x 132 f32

    int tid  = threadIdx.x;
    int w    = tid >> 6;
    int lane = tid & 63;
    int wr = w >> 1, wc = w & 1;
    int bm, bn;
    xcd_decode<2>(gridDim.x, bm, bn);
    int srow = lane >> 2;
    int scol = ((lane & 3) ^ ((lane >> 3) & 3)) * 8;
    int c = lane & 15, hi = lane >> 4;
    int hs = (hi ^ ((c >> 1) & 3)) * 8;

    f32x4 acc[4][4] = {};

    auto stage = [&](unsigned short* asd, unsigned short* bsd, int k0) {
        #pragma unroll
        for (int i = 0; i < 2; ++i) {
            int ra = w * 32 + i * 16;
            gload_lds16(A + (size_t)(bm + ra + srow) * 512 + k0 + scol, asd + ra * 32);
            gload_lds16(W + (size_t)(bn + ra + srow) * 512 + k0 + scol, bsd + ra * 32);
        }
    };
    auto frags = [&](const unsigned short* asd, const unsigned short* bsd,
                     bf16x8* af, bf16x8* bf) {
        #pragma unroll
        for (int mi = 0; mi < 4; ++mi)
            af[mi] = *(const bf16x8*)&asd[(wr * 64 + mi * 16 + c) * 32 + hs];
        #pragma unroll
        for (int ni = 0; ni < 4; ++ni)
            bf[ni] = *(const bf16x8*)&bsd[(wc * 64 + ni * 16 + c) * 32 + hs];
    };
    auto domfma = [&](bf16x8* af, bf16x8* bf) {
        #pragma unroll
        for (int mi = 0; mi < 4; ++mi)
            #pragma unroll
            for (int ni = 0; ni < 4; ++ni)
                acc[mi][ni] = __builtin_amdgcn_mfma_f32_16x16x32_bf16(
                    af[mi], bf[ni], acc[mi][ni], 0, 0, 0);
    };

    stage(As0, Bs0, 0);
    __syncthreads();
    for (int t = 0; t < 16; t += 2) {
        {
            bf16x8 af[4], bf[4];
            frags(As0, Bs0, af, bf);
            stage(As1, Bs1, (t + 1) * 32);
            domfma(af, bf);
            __syncthreads();
        }
        {
            bf16x8 af[4], bf[4];
            frags(As1, Bs1, af, bf);
            if (t + 2 < 16) stage(As0, Bs0, (t + 2) * 32);
            domfma(af, bf);
            __syncthreads();
        }
    }

    // 4 chunks of 32 rows: stage f32 -> coalesced readback + residual + store
    #pragma unroll
    for (int c2 = 0; c2 < 4; ++c2) {
        if (wr == (c2 >> 1)) {
            int mi0 = (c2 & 1) * 2;
            #pragma unroll
            for (int mm = 0; mm < 2; ++mm) {
                #pragma unroll
                for (int ni = 0; ni < 4; ++ni) {
                    int colb = wc * 64 + ni * 16 + c;
                    float bv = bias[bn + colb];
                    #pragma unroll
                    for (int r = 0; r < 4; ++r)
                        stg[(mm * 16 + hi * 4 + r) * 132 + colb] =
                            acc[mi0 + mm][ni][r] + bv;
                }
            }
        }
        __syncthreads();
        #pragma unroll
        for (int i = 0; i < 4; ++i) {
            int lr = i * 8 + (tid >> 5);         // 0..31
            int t = bm + c2 * 32 + lr;
            int rr = t2rr(t);
            int col4 = (tid & 31) * 4;
            float4 v = *(const float4*)&stg[lr * 132 + col4];
            uint2 rv = *(const uint2*)&x1[(size_t)t * C_ + bn + col4];
            v.x += bf2f(rv.x & 0xffff);
            v.y += bf2f(rv.x >> 16);
            v.z += bf2f(rv.y & 0xffff);
            v.w += bf2f(rv.y >> 16);
            *(float4*)&dout[(size_t)rr * C_ + bn + col4] = v;
        }
        __syncthreads();
    }
}

// ---------------------------------------------------------------------------
// MFMA window attention (unchanged)
// ---------------------------------------------------------------------------
__global__ __launch_bounds__(256) void mattn(
    const unsigned short* __restrict__ qkv, unsigned short* __restrict__ o_win)
{
    __shared__ __align__(16) unsigned short P_lds[4][64][72];
    int wave = threadIdx.x >> 6, lane = threadIdx.x & 63;
    int c = lane & 15, hi = lane >> 4;
    int wh = blockIdx.x * 4 + wave;
    int win = wh >> 3, head = wh & 7;
    const unsigned short* qb = qkv + (size_t)wh * WHSZ;
    const unsigned short* kb = qb + (size_t)NWH * WHSZ;
    const unsigned short* vb = kb + (size_t)NWH * WHSZ;

    bf16x8 af[4], bk[4];
    #pragma unroll
    for (int mi = 0; mi < 4; ++mi)
        af[mi] = *(const bf16x8*)(qb + (mi * 16 + c) * HD + hi * 8);
    #pragma unroll
    for (int ni = 0; ni < 4; ++ni)
        bk[ni] = *(const bf16x8*)(kb + (ni * 16 + c) * HD + hi * 8);

    f32x4 sacc[4][4] = {};
    #pragma unroll
    for (int mi = 0; mi < 4; ++mi)
        #pragma unroll
        for (int ni = 0; ni < 4; ++ni)
            sacc[mi][ni] = __builtin_amdgcn_mfma_f32_16x16x32_bf16(
                af[mi], bk[ni], sacc[mi][ni], 0, 0, 0);

    const float scale = 0.17677669529663687f;
    float inv_[4][4];
    #pragma unroll
    for (int mi = 0; mi < 4; ++mi) {
        #pragma unroll
        for (int r = 0; r < 4; ++r) {
            float sv[4];
            float m = -1e30f;
            #pragma unroll
            for (int ni = 0; ni < 4; ++ni) {
                float v = sacc[mi][ni][r] * scale;
                v = (ni * 16 + c < L_) ? v : -1e30f;
                sv[ni] = v;
                m = fmaxf(m, v);
            }
            #pragma unroll
            for (int msk = 1; msk < 16; msk <<= 1)
                m = fmaxf(m, __shfl_xor(m, msk, 64));
            float sum = 0.f;
            unsigned short pb[4];
            #pragma unroll
            for (int ni = 0; ni < 4; ++ni) {
                float p = __expf(sv[ni] - m);
                sum += p;
                pb[ni] = f2bf(p);
            }
            #pragma unroll
            for (int msk = 1; msk < 16; msk <<= 1)
                sum += __shfl_xor(sum, msk, 64);
            inv_[mi][r] = 1.0f / sum;
            int q = mi * 16 + hi * 4 + r;
            #pragma unroll
            for (int ni = 0; ni < 4; ++ni)
                P_lds[wave][q][ni * 16 + c] = pb[ni];
        }
    }

    f32x4 oacc[4][2] = {};
    #pragma unroll
    for (int ks = 0; ks < 2; ++ks) {
        bf16x8 pa[4], bv[2];
        #pragma unroll
        for (int mi = 0; mi < 4; ++mi)
            pa[mi] = *(const bf16x8*)&P_lds[wave][mi * 16 + c][ks * 32 + hi * 8];
        #pragma unroll
        for (int ni = 0; ni < 2; ++ni)
            bv[ni] = *(const bf16x8*)(vb + ((ks * 4 + hi) * HD + ni * 16 + c) * 8);
        #pragma unroll
        for (int mi = 0; mi < 4; ++mi)
            #pragma unroll
            for (int ni = 0; ni < 2; ++ni)
                oacc[mi][ni] = __builtin_amdgcn_mfma_f32_16x16x32_bf16(
                    pa[mi], bv[ni], oacc[mi][ni], 0, 0, 0);
    }

    #pragma unroll
    for (int mi = 0; mi < 4; ++mi) {
        #pragma unroll
        for (int r = 0; r < 4; ++r) {
            int q = mi * 16 + hi * 4 + r;
            if (q < L_) {
                size_t rowoff = ((size_t)(win * L_ + q)) * C_ + head * HD;
                float iv = inv_[mi][r];
                #pragma unroll
                for (int ni = 0; ni < 2; ++ni)
                    o_win[rowoff + ni * 16 + c] = f2bf(oacc[mi][ni][r] * iv);
            }
        }
    }
}

// ---------------------------------------------------------------------------
extern "C" void kernel_launch(void* const* d_in, const int* in_sizes, int n_in,
                              void* d_out, int out_size, void* d_ws, size_t ws_size,
                              hipStream_t stream)
{
    (void)in_sizes; (void)n_in; (void)out_size; (void)ws_size;
    const float* x    = (const float*)d_in[0];
    const float* n1g  = (const float*)d_in[3];
    const float* n1b  = (const float*)d_in[4];
    const float* wqkv = (const float*)d_in[5];
    const float* bqkv = (const float*)d_in[6];
    const float* wout = (const float*)d_in[7];
    const float* bout = (const float*)d_in[8];
    const float* n2g  = (const float*)d_in[9];
    const float* n2b  = (const float*)d_in[10];
    const float* w1   = (const float*)d_in[11];
    const float* b1   = (const float*)d_in[12];
    const float* w2   = (const float*)d_in[13];
    const float* b2   = (const float*)d_in[14];
    float* out = (float*)d_out;

    // workspace layout (bf16 shorts)
    unsigned short* bufA_bf = (unsigned short*)d_ws;                 // M*256 (LN1 out, then o_win)
    unsigned short* qkv_bf  = bufA_bf + (size_t)M_ * C_;             // 3*NWH*2048 (Q,K,V'; later gelu M*512)
    unsigned short* x1_bf   = qkv_bf + (size_t)3 * NWH * WHSZ;       // M*256
    unsigned short* ln2_bf  = x1_bf + (size_t)M_ * C_;               // M*256
    unsigned short* wqkv_bf = ln2_bf + (size_t)M_ * C_;
    unsigned short* wout_bf = wqkv_bf + 768 * 256;
    unsigned short* w1_bf   = wout_bf + 256 * 256;
    unsigned short* w2_bf   = w1_bf + 512 * 256;

    // 0) weights -> bf16
    cvt_kernel<<<(768 * 256 + 255) / 256, 256, 0, stream>>>(wqkv, wqkv_bf, 768 * 256);
    cvt_kernel<<<(256 * 256 + 255) / 256, 256, 0, stream>>>(wout, wout_bf, 256 * 256);
    cvt_kernel<<<(512 * 256 + 255) / 256, 256, 0, stream>>>(w1, w1_bf, 512 * 256);
    cvt_kernel<<<(256 * 512 + 255) / 256, 256, 0, stream>>>(w2, w2_bf, 256 * 512);

    // 1) LN1 + window partition -> bufA_bf
    ln_kernel<<<M_ / 4, 256, 0, stream>>>(x, n1g, n1b, bufA_bf);

    // 2) QKV GEMM -> Q/K/V' planes  (XCD-chunked, 784*6 blocks)
    mgemm<0, 6><<<(M_ / GBM) * 6, 256, 0, stream>>>(
        bufA_bf, wqkv_bf, bqkv, qkv_bf, M_, 3 * C_, C_);

    // 3) MFMA window attention -> o_win (bufA_bf)
    mattn<<<NWH / 4, 256, 0, stream>>>(qkv_bf, bufA_bf);

    // 4) out-proj + residual + LN2 fused -> x1_bf, ln2_bf (both windowed)
    mgemm_ln<<<M_ / 128, 512, 0, stream>>>(
        bufA_bf, wout_bf, bout, x, n2g, n2b, x1_bf, ln2_bf);

    // 5) MLP fc1 + GELU -> qkv_bf region  (XCD-chunked, 784*4 blocks)
    mgemm<2, 4><<<(M_ / GBM) * 4, 256, 0, stream>>>(
        ln2_bf, w1_bf, b1, qkv_bf, M_, MLPH, C_);

    // 6) MLP fc2 + residual(x1_bf) -> d_out  (XCD-chunked, 784*2 blocks)
    mgemm_out<<<(M_ / 128) * 2, 256, 0, stream>>>(
        qkv_bf, w2_bf, b2, x1_bf, out);
}